// Round 1
// baseline (167.079 us; speedup 1.0000x reference)
//
#include <hip/hip_runtime.h>

#define H 64
#define R 5

// One thread per edge. Row gathers are float4-vectorized (16 B/lane); rel_emb
// accesses are thread-uniform constants -> compiler emits s_load + SGPR-operand
// v_fma_f32, keeping the 5x64 dot products off the LDS pipe entirely.
__global__ __launch_bounds__(256) void edge_decoder_kernel(
    const float* __restrict__ zu,
    const float* __restrict__ zm,
    const float* __restrict__ rel,
    const int*   __restrict__ idx,
    float*       __restrict__ out,
    int E)
{
    int e = blockIdx.x * blockDim.x + threadIdx.x;
    if (e >= E) return;

    int su = idx[e];       // edge_label_index[0][e]
    int sm = idx[E + e];   // edge_label_index[1][e]

    const float4* a = (const float4*)(zu + (long long)su * H);
    const float4* b = (const float4*)(zm + (long long)sm * H);

    float s0 = 0.f, s1 = 0.f, s2 = 0.f, s3 = 0.f, s4 = 0.f;

#pragma unroll
    for (int c = 0; c < H / 4; ++c) {
        float4 av = a[c];
        float4 bv = b[c];
        float p0 = av.x * bv.x;
        float p1 = av.y * bv.y;
        float p2 = av.z * bv.z;
        float p3 = av.w * bv.w;
        const int h = c * 4;
        // rel indices are compile-time constants -> scalar (SGPR) operands
        s0 = fmaf(p0, rel[0 * H + h + 0], s0);
        s0 = fmaf(p1, rel[0 * H + h + 1], s0);
        s0 = fmaf(p2, rel[0 * H + h + 2], s0);
        s0 = fmaf(p3, rel[0 * H + h + 3], s0);
        s1 = fmaf(p0, rel[1 * H + h + 0], s1);
        s1 = fmaf(p1, rel[1 * H + h + 1], s1);
        s1 = fmaf(p2, rel[1 * H + h + 2], s1);
        s1 = fmaf(p3, rel[1 * H + h + 3], s1);
        s2 = fmaf(p0, rel[2 * H + h + 0], s2);
        s2 = fmaf(p1, rel[2 * H + h + 1], s2);
        s2 = fmaf(p2, rel[2 * H + h + 2], s2);
        s2 = fmaf(p3, rel[2 * H + h + 3], s2);
        s3 = fmaf(p0, rel[3 * H + h + 0], s3);
        s3 = fmaf(p1, rel[3 * H + h + 1], s3);
        s3 = fmaf(p2, rel[3 * H + h + 2], s3);
        s3 = fmaf(p3, rel[3 * H + h + 3], s3);
        s4 = fmaf(p0, rel[4 * H + h + 0], s4);
        s4 = fmaf(p1, rel[4 * H + h + 1], s4);
        s4 = fmaf(p2, rel[4 * H + h + 2], s4);
        s4 = fmaf(p3, rel[4 * H + h + 3], s4);
    }

    // softmax over 5 scores + expected rating sum_r r*p_r
    float m = fmaxf(fmaxf(fmaxf(s0, s1), fmaxf(s2, s3)), s4);
    float e0 = __expf(s0 - m);
    float e1 = __expf(s1 - m);
    float e2 = __expf(s2 - m);
    float e3 = __expf(s3 - m);
    float e4 = __expf(s4 - m);
    float den = e0 + e1 + e2 + e3 + e4;
    float num = fmaf(4.f, e4, fmaf(3.f, e3, fmaf(2.f, e2, e1)));
    out[e] = num / den;
}

extern "C" void kernel_launch(void* const* d_in, const int* in_sizes, int n_in,
                              void* d_out, int out_size, void* d_ws, size_t ws_size,
                              hipStream_t stream) {
    const float* zu  = (const float*)d_in[0];   // z_user   [100000,64]
    const float* zm  = (const float*)d_in[1];   // z_movie  [50000,64]
    const float* rel = (const float*)d_in[2];   // rel_emb  [5,64]
    const int*   idx = (const int*)d_in[3];     // edge_label_index [2,E]
    float* out = (float*)d_out;

    int E = in_sizes[3] / 2;
    int block = 256;
    int grid = (E + block - 1) / block;
    edge_decoder_kernel<<<grid, block, 0, stream>>>(zu, zm, rel, idx, out, E);
}

// Round 2
// 148.027 us; speedup vs baseline: 1.1287x; 1.1287x over previous
//
#include <hip/hip_runtime.h>

#define H 64
#define R 5

// 16 lanes cooperate per edge: lane l loads float4 chunk l of the 64-float row.
// One wave instruction loads full rows for 4 edges; 4 lanes share each 64B
// cacheline -> intra-instruction coalescing (16 txns/instr vs 64 in the
// thread-per-edge layout). Dot products finish with a 4-step shfl_xor
// butterfly over the 16-lane group.
__global__ __launch_bounds__(256) void edge_decoder_kernel(
    const float4* __restrict__ zu4,   // z_user  as [NUM_USERS  * 16] float4
    const float4* __restrict__ zm4,   // z_movie as [NUM_MOVIES * 16] float4
    const float4* __restrict__ rel4,  // rel_emb as [R * 16] float4
    const int*    __restrict__ idx,   // [2, E]
    float*        __restrict__ out,   // [E]
    int E)
{
    int tid = blockIdx.x * blockDim.x + threadIdx.x;
    int l   = threadIdx.x & 15;   // chunk index within the row
    int e   = tid >> 4;           // edge handled by this 16-lane group
    if (e >= E) return;

    int su = idx[e];        // user id (broadcast load within group)
    int sm = idx[E + e];    // movie id

    float4 av = zu4[su * 16 + l];
    float4 bv = zm4[sm * 16 + l];

    float p0 = av.x * bv.x;
    float p1 = av.y * bv.y;
    float p2 = av.z * bv.z;
    float p3 = av.w * bv.w;

    float s[R];
#pragma unroll
    for (int r = 0; r < R; ++r) {
        float4 w = rel4[r * 16 + l];   // L1-resident after first wave
        s[r] = fmaf(p0, w.x, fmaf(p1, w.y, fmaf(p2, w.z, p3 * w.w)));
    }

    // butterfly reduce each score across the 16-lane group
#pragma unroll
    for (int m = 1; m < 16; m <<= 1) {
#pragma unroll
        for (int r = 0; r < R; ++r)
            s[r] += __shfl_xor(s[r], m, 16);
    }

    if (l == 0) {
        float mx = fmaxf(fmaxf(fmaxf(s[0], s[1]), fmaxf(s[2], s[3])), s[4]);
        float e0 = __expf(s[0] - mx);
        float e1 = __expf(s[1] - mx);
        float e2 = __expf(s[2] - mx);
        float e3 = __expf(s[3] - mx);
        float e4 = __expf(s[4] - mx);
        float den = e0 + e1 + e2 + e3 + e4;
        float num = fmaf(4.f, e4, fmaf(3.f, e3, fmaf(2.f, e2, e1)));
        out[e] = num / den;   // 4 consecutive floats per wave -> 1 txn
    }
}

extern "C" void kernel_launch(void* const* d_in, const int* in_sizes, int n_in,
                              void* d_out, int out_size, void* d_ws, size_t ws_size,
                              hipStream_t stream) {
    const float4* zu4  = (const float4*)d_in[0];   // z_user   [100000,64]
    const float4* zm4  = (const float4*)d_in[1];   // z_movie  [50000,64]
    const float4* rel4 = (const float4*)d_in[2];   // rel_emb  [5,64]
    const int*    idx  = (const int*)d_in[3];      // edge_label_index [2,E]
    float* out = (float*)d_out;

    int E = in_sizes[3] / 2;
    long long threads = (long long)E * 16;
    int block = 256;
    int grid = (int)((threads + block - 1) / block);
    edge_decoder_kernel<<<grid, block, 0, stream>>>(zu4, zm4, rel4, idx, out, E);
}

// Round 3
// 140.480 us; speedup vs baseline: 1.1893x; 1.0537x over previous
//
#include <hip/hip_runtime.h>

#define H 64
#define R 5

typedef float v2f __attribute__((ext_vector_type(2)));

// fused a*b+c on float2 -> v_pk_fma_f32 (full-rate dual fp32 on CDNA)
static __device__ __forceinline__ v2f fma2(v2f a, v2f b, v2f c) {
#if __has_builtin(__builtin_elementwise_fma)
    return __builtin_elementwise_fma(a, b, c);
#else
    return a * b + c;   // HIP default -ffp-contract=fast -> v_pk_fma_f32
#endif
}

// G=4: a quad (4 lanes) handles one edge. Load instr i: lane l reads float4
// chunk 4i+l, so each quad touches one contiguous 64B line per instr ->
// minimal 8 cacheline txns/edge. Reduction is 2 quad_perm-DPP steps (10
// instrs per 16 edges vs 40 per 4 edges in the G=16 version); softmax/exp
// cost amortizes over 16 edges/wave. Dot-product core uses packed fp32.
__global__ __launch_bounds__(256) void edge_decoder_kernel(
    const float4* __restrict__ zu4,   // z_user  as [NUM_USERS  * 16] float4
    const float4* __restrict__ zm4,   // z_movie as [NUM_MOVIES * 16] float4
    const float4* __restrict__ rel4,  // rel_emb as [R * 16] float4
    const int*    __restrict__ idx,   // [2, E]
    float*        __restrict__ out,   // [E]
    int E)
{
    int tid = blockIdx.x * blockDim.x + threadIdx.x;
    int l   = threadIdx.x & 3;    // lane within quad
    int e   = tid >> 2;           // edge for this quad
    if (e >= E) return;

    int su = idx[e];
    int sm = idx[E + e];

    const float4* arow = zu4 + su * 16;
    const float4* brow = zm4 + sm * 16;

    // products for this lane's 4 chunks (chunk c = 4i + l)
    v2f plo[4], phi[4];
#pragma unroll
    for (int i = 0; i < 4; ++i) {
        float4 av = arow[4 * i + l];
        float4 bv = brow[4 * i + l];
        v2f alo = {av.x, av.y}, ahi = {av.z, av.w};
        v2f blo = {bv.x, bv.y}, bhi = {bv.z, bv.w};
        plo[i] = alo * blo;   // v_pk_mul_f32
        phi[i] = ahi * bhi;
    }

    float s[R];
#pragma unroll
    for (int r = 0; r < R; ++r) {
        v2f acc = {0.f, 0.f};
#pragma unroll
        for (int i = 0; i < 4; ++i) {
            float4 w = rel4[r * 16 + 4 * i + l];   // L1 broadcast (same line per wave)
            v2f wlo = {w.x, w.y}, whi = {w.z, w.w};
            acc = fma2(plo[i], wlo, acc);
            acc = fma2(phi[i], whi, acc);
        }
        s[r] = acc.x + acc.y;
    }

    // reduce across the quad: xor1, xor2 -> quad_perm DPP-fused adds
#pragma unroll
    for (int r = 0; r < R; ++r) s[r] += __shfl_xor(s[r], 1);
#pragma unroll
    for (int r = 0; r < R; ++r) s[r] += __shfl_xor(s[r], 2);

    if (l == 0) {
        float mx = fmaxf(fmaxf(fmaxf(s[0], s[1]), fmaxf(s[2], s[3])), s[4]);
        float e0 = __expf(s[0] - mx);
        float e1 = __expf(s[1] - mx);
        float e2 = __expf(s[2] - mx);
        float e3 = __expf(s[3] - mx);
        float e4 = __expf(s[4] - mx);
        float den = e0 + e1 + e2 + e3 + e4;
        float num = fmaf(4.f, e4, fmaf(3.f, e3, fmaf(2.f, e2, e1)));
        out[e] = num * __frcp_rn(den);
    }
}

extern "C" void kernel_launch(void* const* d_in, const int* in_sizes, int n_in,
                              void* d_out, int out_size, void* d_ws, size_t ws_size,
                              hipStream_t stream) {
    const float4* zu4  = (const float4*)d_in[0];   // z_user   [100000,64]
    const float4* zm4  = (const float4*)d_in[1];   // z_movie  [50000,64]
    const float4* rel4 = (const float4*)d_in[2];   // rel_emb  [5,64]
    const int*    idx  = (const int*)d_in[3];      // edge_label_index [2,E]
    float* out = (float*)d_out;

    int E = in_sizes[3] / 2;
    long long threads = (long long)E * 4;
    int block = 256;
    int grid = (int)((threads + block - 1) / block);
    edge_decoder_kernel<<<grid, block, 0, stream>>>(zu4, zm4, rel4, idx, out, E);
}

// Round 5
// 131.728 us; speedup vs baseline: 1.2684x; 1.0664x over previous
//
#include <hip/hip_runtime.h>
#include <hip/hip_fp16.h>

#define H 64
#define R 5

typedef float v2f __attribute__((ext_vector_type(2)));

static __device__ __forceinline__ v2f fma2(v2f a, v2f b, v2f c) {
#if __has_builtin(__builtin_elementwise_fma)
    return __builtin_elementwise_fma(a, b, c);
#else
    return a * b + c;
#endif
}

// pack two fp32 -> fp16 pair (RNE) in one uint
static __device__ __forceinline__ unsigned h2pair(float a, float b) {
    __half2 h = __floats2half2_rn(a, b);
    return *(const unsigned*)&h;
}

// unpack fp16 pair -> v2f (v_cvt_f32_f16 lo/hi, full-rate)
static __device__ __forceinline__ v2f unpk(unsigned u) {
    __half2 h = *(const __half2*)&u;
    float2 f = __half22float2(h);
    return (v2f){f.x, f.y};
}

// Streaming prep: convert z_user / z_movie rows to fp16 (RNE) in workspace.
// One thread converts 8 floats (2x float4 in -> 1x uint4 out).
// fp16 not bf16: 11-bit mantissa (rel err 4.9e-4) vs bf16's 8-bit (3.9e-3);
// bf16 measured absmax 0.109 > 0.08 threshold, fp16 scales that to ~0.014.
// N(0,1) inputs, |z|max ~5.5 -> no fp16 range issues.
__global__ __launch_bounds__(256) void convert_f16_kernel(
    const float4* __restrict__ zu4, const float4* __restrict__ zm4,
    uint4* __restrict__ wu, uint4* __restrict__ wm,
    int n_u_chunks, int n_m_chunks)
{
    int t = blockIdx.x * blockDim.x + threadIdx.x;
    const float4* src;
    uint4* dst;
    int c;
    if (t < n_u_chunks)                  { src = zu4; dst = wu; c = t; }
    else if (t < n_u_chunks + n_m_chunks){ src = zm4; dst = wm; c = t - n_u_chunks; }
    else return;
    float4 f0 = src[2 * c];
    float4 f1 = src[2 * c + 1];
    uint4 o;
    o.x = h2pair(f0.x, f0.y);
    o.y = h2pair(f0.z, f0.w);
    o.z = h2pair(f1.x, f1.y);
    o.w = h2pair(f1.z, f1.w);
    dst[c] = o;
}

// Main pass, G=4 quads per edge, fp16 rows (128B = 2 cachelines).
// Lane l, instr i reads the 16B chunk (4i+l) -> each quad covers one
// contiguous 64B line per instr -> minimal 4 line-txns per edge.
// rel_emb stays fp32 (L1-resident); accumulation all fp32.
__global__ __launch_bounds__(256) void edge_decoder_f16_kernel(
    const uint4*  __restrict__ wu,    // fp16 rows, 8 uint4 per row
    const uint4*  __restrict__ wm,
    const float4* __restrict__ rel4,  // rel_emb as [R*16] float4
    const int*    __restrict__ idx,
    float*        __restrict__ out,
    int E)
{
    int tid = blockIdx.x * blockDim.x + threadIdx.x;
    int l   = threadIdx.x & 3;
    int e   = tid >> 2;
    if (e >= E) return;

    int su = idx[e];
    int sm = idx[E + e];

    const uint4* ra = wu + su * 8;
    const uint4* rb = wm + sm * 8;
    uint4 a0 = ra[l];
    uint4 a1 = ra[4 + l];
    uint4 b0 = rb[l];
    uint4 b1 = rb[4 + l];

    // 16 products for this lane's h-values: i=0 -> h in [8l,8l+8),
    // i=1 -> h in [32+8l, 32+8l+8)
    v2f p[8];
    p[0] = unpk(a0.x) * unpk(b0.x);
    p[1] = unpk(a0.y) * unpk(b0.y);
    p[2] = unpk(a0.z) * unpk(b0.z);
    p[3] = unpk(a0.w) * unpk(b0.w);
    p[4] = unpk(a1.x) * unpk(b1.x);
    p[5] = unpk(a1.y) * unpk(b1.y);
    p[6] = unpk(a1.z) * unpk(b1.z);
    p[7] = unpk(a1.w) * unpk(b1.w);

    float s[R];
#pragma unroll
    for (int r = 0; r < R; ++r) {
        float4 w0 = rel4[r * 16 + 2 * l];
        float4 w1 = rel4[r * 16 + 2 * l + 1];
        float4 w2 = rel4[r * 16 + 8 + 2 * l];
        float4 w3 = rel4[r * 16 + 8 + 2 * l + 1];
        v2f acc = {0.f, 0.f};
        acc = fma2(p[0], (v2f){w0.x, w0.y}, acc);
        acc = fma2(p[1], (v2f){w0.z, w0.w}, acc);
        acc = fma2(p[2], (v2f){w1.x, w1.y}, acc);
        acc = fma2(p[3], (v2f){w1.z, w1.w}, acc);
        acc = fma2(p[4], (v2f){w2.x, w2.y}, acc);
        acc = fma2(p[5], (v2f){w2.z, w2.w}, acc);
        acc = fma2(p[6], (v2f){w3.x, w3.y}, acc);
        acc = fma2(p[7], (v2f){w3.z, w3.w}, acc);
        s[r] = acc.x + acc.y;
    }

#pragma unroll
    for (int r = 0; r < R; ++r) s[r] += __shfl_xor(s[r], 1);
#pragma unroll
    for (int r = 0; r < R; ++r) s[r] += __shfl_xor(s[r], 2);

    if (l == 0) {
        float mx = fmaxf(fmaxf(fmaxf(s[0], s[1]), fmaxf(s[2], s[3])), s[4]);
        float e0 = __expf(s[0] - mx);
        float e1 = __expf(s[1] - mx);
        float e2 = __expf(s[2] - mx);
        float e3 = __expf(s[3] - mx);
        float e4 = __expf(s[4] - mx);
        float den = e0 + e1 + e2 + e3 + e4;
        float num = fmaf(4.f, e4, fmaf(3.f, e3, fmaf(2.f, e2, e1)));
        out[e] = num * __frcp_rn(den);
    }
}

// ---- fp32 fallback (round-3 kernel) if ws is too small for fp16 tables ----
__global__ __launch_bounds__(256) void edge_decoder_f32_kernel(
    const float4* __restrict__ zu4, const float4* __restrict__ zm4,
    const float4* __restrict__ rel4, const int* __restrict__ idx,
    float* __restrict__ out, int E)
{
    int tid = blockIdx.x * blockDim.x + threadIdx.x;
    int l   = threadIdx.x & 3;
    int e   = tid >> 2;
    if (e >= E) return;
    int su = idx[e];
    int sm = idx[E + e];
    const float4* arow = zu4 + su * 16;
    const float4* brow = zm4 + sm * 16;
    v2f plo[4], phi[4];
#pragma unroll
    for (int i = 0; i < 4; ++i) {
        float4 av = arow[4 * i + l];
        float4 bv = brow[4 * i + l];
        v2f alo = {av.x, av.y}, ahi = {av.z, av.w};
        v2f blo = {bv.x, bv.y}, bhi = {bv.z, bv.w};
        plo[i] = alo * blo;
        phi[i] = ahi * bhi;
    }
    float s[R];
#pragma unroll
    for (int r = 0; r < R; ++r) {
        v2f acc = {0.f, 0.f};
#pragma unroll
        for (int i = 0; i < 4; ++i) {
            float4 w = rel4[r * 16 + 4 * i + l];
            acc = fma2(plo[i], (v2f){w.x, w.y}, acc);
            acc = fma2(phi[i], (v2f){w.z, w.w}, acc);
        }
        s[r] = acc.x + acc.y;
    }
#pragma unroll
    for (int r = 0; r < R; ++r) s[r] += __shfl_xor(s[r], 1);
#pragma unroll
    for (int r = 0; r < R; ++r) s[r] += __shfl_xor(s[r], 2);
    if (l == 0) {
        float mx = fmaxf(fmaxf(fmaxf(s[0], s[1]), fmaxf(s[2], s[3])), s[4]);
        float e0 = __expf(s[0] - mx);
        float e1 = __expf(s[1] - mx);
        float e2 = __expf(s[2] - mx);
        float e3 = __expf(s[3] - mx);
        float e4 = __expf(s[4] - mx);
        float den = e0 + e1 + e2 + e3 + e4;
        float num = fmaf(4.f, e4, fmaf(3.f, e3, fmaf(2.f, e2, e1)));
        out[e] = num * __frcp_rn(den);
    }
}

extern "C" void kernel_launch(void* const* d_in, const int* in_sizes, int n_in,
                              void* d_out, int out_size, void* d_ws, size_t ws_size,
                              hipStream_t stream) {
    const float4* zu4  = (const float4*)d_in[0];   // z_user   [NU,64]
    const float4* zm4  = (const float4*)d_in[1];   // z_movie  [NM,64]
    const float4* rel4 = (const float4*)d_in[2];   // rel_emb  [5,64]
    const int*    idx  = (const int*)d_in[3];      // edge_label_index [2,E]
    float* out = (float*)d_out;

    int E  = in_sizes[3] / 2;
    int nu = in_sizes[0] / H;   // user rows
    int nm = in_sizes[1] / H;   // movie rows

    size_t need = (size_t)(nu + nm) * H * 2;   // fp16 tables
    int block = 256;

    if (ws_size >= need) {
        uint4* wu = (uint4*)d_ws;              // nu*8 uint4
        uint4* wm = wu + (size_t)nu * 8;       // nm*8 uint4

        int n_u_chunks = nu * (H / 8);
        int n_m_chunks = nm * (H / 8);
        int conv_threads = n_u_chunks + n_m_chunks;
        int conv_grid = (conv_threads + block - 1) / block;
        convert_f16_kernel<<<conv_grid, block, 0, stream>>>(
            zu4, zm4, wu, wm, n_u_chunks, n_m_chunks);

        long long threads = (long long)E * 4;
        int grid = (int)((threads + block - 1) / block);
        edge_decoder_f16_kernel<<<grid, block, 0, stream>>>(
            wu, wm, rel4, idx, out, E);
    } else {
        long long threads = (long long)E * 4;
        int grid = (int)((threads + block - 1) / block);
        edge_decoder_f32_kernel<<<grid, block, 0, stream>>>(
            zu4, zm4, rel4, idx, out, E);
    }
}

// Round 6
// 127.607 us; speedup vs baseline: 1.3093x; 1.0323x over previous
//
#include <hip/hip_runtime.h>
#include <hip/hip_fp16.h>

#define H 64
#define R 5

typedef float    v2f __attribute__((ext_vector_type(2)));
typedef _Float16 v2h __attribute__((ext_vector_type(2)));

static __device__ __forceinline__ v2f fma2(v2f a, v2f b, v2f c) {
#if __has_builtin(__builtin_elementwise_fma)
    return __builtin_elementwise_fma(a, b, c);
#else
    return a * b + c;
#endif
}

// fp16 2-way dot with fp32 accumulate: v_dot2_f32_f16
static __device__ __forceinline__ float dot2(v2h a, v2h b, float c) {
#if __has_builtin(__builtin_amdgcn_fdot2)
    return __builtin_amdgcn_fdot2(a, b, c, false);
#else
    return (float)a.x * (float)b.x + (float)a.y * (float)b.y + c;
#endif
}

static __device__ __forceinline__ v2h bch(unsigned u) {
    return __builtin_bit_cast(v2h, u);
}

// pack two fp32 -> fp16 pair (RNE) in one uint
static __device__ __forceinline__ unsigned h2pair(float a, float b) {
    __half2 h = __floats2half2_rn(a, b);
    return *(const unsigned*)&h;
}

// Streaming prep: z_user, z_movie AND rel_emb -> fp16 in workspace.
// One thread converts 8 floats (2x float4 in -> 1x uint4 out).
__global__ __launch_bounds__(256) void convert_f16_kernel(
    const float4* __restrict__ zu4, const float4* __restrict__ zm4,
    const float4* __restrict__ rel4,
    uint4* __restrict__ wu, uint4* __restrict__ wm, uint4* __restrict__ wr,
    int n_u_chunks, int n_m_chunks, int n_r_chunks)
{
    int t = blockIdx.x * blockDim.x + threadIdx.x;
    const float4* src;
    uint4* dst;
    int c;
    if (t < n_u_chunks)                   { src = zu4;  dst = wu; c = t; }
    else if (t < n_u_chunks + n_m_chunks) { src = zm4;  dst = wm; c = t - n_u_chunks; }
    else if (t < n_u_chunks + n_m_chunks + n_r_chunks)
                                          { src = rel4; dst = wr; c = t - n_u_chunks - n_m_chunks; }
    else return;
    float4 f0 = src[2 * c];
    float4 f1 = src[2 * c + 1];
    uint4 o;
    o.x = h2pair(f0.x, f0.y);
    o.y = h2pair(f0.z, f0.w);
    o.z = h2pair(f1.x, f1.y);
    o.w = h2pair(f1.z, f1.w);
    dst[c] = o;
}

// Main pass: each quad (4 lanes) handles 4 edges -> 16 independent row loads
// in flight per wave (4x the MLP of 1-edge/quad), rel fragments register-
// resident and amortized over 4 edges, softmax on all 64 lanes (lane j of a
// quad owns edge base+j), coalesced dword store.
// Row = 128B fp16 = 2 cachelines; lane l reads chunks l and 4+l, so each quad
// covers one contiguous 64B line per load instr (minimal line txns).
// Dot core: v_pk_mul_f16 products + v_dot2_f32_f16 (fp32 accumulate).
__global__ __launch_bounds__(256) void edge_decoder_f16d_kernel(
    const uint4* __restrict__ wu,    // fp16 rows, 8 uint4 per row
    const uint4* __restrict__ wm,
    const uint4* __restrict__ wr,    // fp16 rel_emb, 8 uint4 per relation
    const int*   __restrict__ idx,
    float*       __restrict__ out,
    int E)
{
    int tid  = blockIdx.x * blockDim.x + threadIdx.x;
    int l    = tid & 3;
    int base = (tid >> 2) << 2;      // first edge of this quad
    if (base >= E) return;           // whole quad out of range

    int mye = base + l;
    int su_l = 0, sm_l = 0;
    if (mye < E) { su_l = idx[mye]; sm_l = idx[E + mye]; }

    // rel fragments for this lane: w0[r] covers h in [8l,8l+8),
    // w1[r] covers h in [32+8l, 32+8l+8). L1-resident, reused for 4 edges.
    uint4 w0[R], w1[R];
#pragma unroll
    for (int r = 0; r < R; ++r) {
        w0[r] = wr[r * 8 + l];
        w1[r] = wr[r * 8 + 4 + l];
    }

    // issue all 16 row loads (4 edges x 2 rows x 2 chunks) back-to-back
    uint4 a0[4], a1[4], b0[4], b1[4];
#pragma unroll
    for (int j = 0; j < 4; ++j) {
        int su = __shfl(su_l, j, 4);
        int sm = __shfl(sm_l, j, 4);
        const uint4* ra = wu + (size_t)su * 8;
        const uint4* rb = wm + (size_t)sm * 8;
        a0[j] = ra[l];
        a1[j] = ra[4 + l];
        b0[j] = rb[l];
        b1[j] = rb[4 + l];
    }

    float s[R][4];
#pragma unroll
    for (int j = 0; j < 4; ++j) {
        v2h p[8];
        p[0] = bch(a0[j].x) * bch(b0[j].x);   // v_pk_mul_f16
        p[1] = bch(a0[j].y) * bch(b0[j].y);
        p[2] = bch(a0[j].z) * bch(b0[j].z);
        p[3] = bch(a0[j].w) * bch(b0[j].w);
        p[4] = bch(a1[j].x) * bch(b1[j].x);
        p[5] = bch(a1[j].y) * bch(b1[j].y);
        p[6] = bch(a1[j].z) * bch(b1[j].z);
        p[7] = bch(a1[j].w) * bch(b1[j].w);
#pragma unroll
        for (int r = 0; r < R; ++r) {
            float acc = 0.f;
            acc = dot2(p[0], bch(w0[r].x), acc);
            acc = dot2(p[1], bch(w0[r].y), acc);
            acc = dot2(p[2], bch(w0[r].z), acc);
            acc = dot2(p[3], bch(w0[r].w), acc);
            acc = dot2(p[4], bch(w1[r].x), acc);
            acc = dot2(p[5], bch(w1[r].y), acc);
            acc = dot2(p[6], bch(w1[r].z), acc);
            acc = dot2(p[7], bch(w1[r].w), acc);
            s[r][j] = acc;
        }
    }

    // quad butterfly: every lane ends with the full sum for all 4 edges
#pragma unroll
    for (int r = 0; r < R; ++r)
#pragma unroll
        for (int j = 0; j < 4; ++j) s[r][j] += __shfl_xor(s[r][j], 1);
#pragma unroll
    for (int r = 0; r < R; ++r)
#pragma unroll
        for (int j = 0; j < 4; ++j) s[r][j] += __shfl_xor(s[r][j], 2);

    // lane l keeps edge l's scores -> softmax on all 64 lanes
    bool c1 = (l & 1) != 0;
    bool c2 = (l & 2) != 0;
    float sc[R];
#pragma unroll
    for (int r = 0; r < R; ++r) {
        float t01 = c1 ? s[r][1] : s[r][0];
        float t23 = c1 ? s[r][3] : s[r][2];
        sc[r] = c2 ? t23 : t01;
    }

    float mx = fmaxf(fmaxf(fmaxf(sc[0], sc[1]), fmaxf(sc[2], sc[3])), sc[4]);
    float e0 = __expf(sc[0] - mx);
    float e1 = __expf(sc[1] - mx);
    float e2 = __expf(sc[2] - mx);
    float e3 = __expf(sc[3] - mx);
    float e4 = __expf(sc[4] - mx);
    float den = e0 + e1 + e2 + e3 + e4;
    float num = fmaf(4.f, e4, fmaf(3.f, e3, fmaf(2.f, e2, e1)));
    if (mye < E) out[mye] = num * __frcp_rn(den);
}

// ---- fp32 fallback (round-3 kernel) if ws is too small for fp16 tables ----
__global__ __launch_bounds__(256) void edge_decoder_f32_kernel(
    const float4* __restrict__ zu4, const float4* __restrict__ zm4,
    const float4* __restrict__ rel4, const int* __restrict__ idx,
    float* __restrict__ out, int E)
{
    int tid = blockIdx.x * blockDim.x + threadIdx.x;
    int l   = threadIdx.x & 3;
    int e   = tid >> 2;
    if (e >= E) return;
    int su = idx[e];
    int sm = idx[E + e];
    const float4* arow = zu4 + su * 16;
    const float4* brow = zm4 + sm * 16;
    v2f plo[4], phi[4];
#pragma unroll
    for (int i = 0; i < 4; ++i) {
        float4 av = arow[4 * i + l];
        float4 bv = brow[4 * i + l];
        v2f alo = {av.x, av.y}, ahi = {av.z, av.w};
        v2f blo = {bv.x, bv.y}, bhi = {bv.z, bv.w};
        plo[i] = alo * blo;
        phi[i] = ahi * bhi;
    }
    float s[R];
#pragma unroll
    for (int r = 0; r < R; ++r) {
        v2f acc = {0.f, 0.f};
#pragma unroll
        for (int i = 0; i < 4; ++i) {
            float4 w = rel4[r * 16 + 4 * i + l];
            acc = fma2(plo[i], (v2f){w.x, w.y}, acc);
            acc = fma2(phi[i], (v2f){w.z, w.w}, acc);
        }
        s[r] = acc.x + acc.y;
    }
#pragma unroll
    for (int r = 0; r < R; ++r) s[r] += __shfl_xor(s[r], 1);
#pragma unroll
    for (int r = 0; r < R; ++r) s[r] += __shfl_xor(s[r], 2);
    if (l == 0) {
        float mx = fmaxf(fmaxf(fmaxf(s[0], s[1]), fmaxf(s[2], s[3])), s[4]);
        float e0 = __expf(s[0] - mx);
        float e1 = __expf(s[1] - mx);
        float e2 = __expf(s[2] - mx);
        float e3 = __expf(s[3] - mx);
        float e4 = __expf(s[4] - mx);
        float den = e0 + e1 + e2 + e3 + e4;
        float num = fmaf(4.f, e4, fmaf(3.f, e3, fmaf(2.f, e2, e1)));
        out[e] = num * __frcp_rn(den);
    }
}

extern "C" void kernel_launch(void* const* d_in, const int* in_sizes, int n_in,
                              void* d_out, int out_size, void* d_ws, size_t ws_size,
                              hipStream_t stream) {
    const float4* zu4  = (const float4*)d_in[0];   // z_user   [NU,64]
    const float4* zm4  = (const float4*)d_in[1];   // z_movie  [NM,64]
    const float4* rel4 = (const float4*)d_in[2];   // rel_emb  [5,64]
    const int*    idx  = (const int*)d_in[3];      // edge_label_index [2,E]
    float* out = (float*)d_out;

    int E  = in_sizes[3] / 2;
    int nu = in_sizes[0] / H;   // user rows
    int nm = in_sizes[1] / H;   // movie rows

    size_t need = (size_t)(nu + nm + R) * H * 2;   // fp16 tables + rel
    int block = 256;

    if (ws_size >= need) {
        uint4* wu = (uint4*)d_ws;              // nu*8 uint4
        uint4* wm = wu + (size_t)nu * 8;       // nm*8 uint4
        uint4* wr = wm + (size_t)nm * 8;       // R*8 uint4

        int n_u_chunks = nu * (H / 8);
        int n_m_chunks = nm * (H / 8);
        int n_r_chunks = R * (H / 8);
        int conv_threads = n_u_chunks + n_m_chunks + n_r_chunks;
        int conv_grid = (conv_threads + block - 1) / block;
        convert_f16_kernel<<<conv_grid, block, 0, stream>>>(
            zu4, zm4, rel4, wu, wm, wr, n_u_chunks, n_m_chunks, n_r_chunks);

        long long threads = (long long)E;      // 1 lane per edge (4 lanes x 4 edges per quad)
        int grid = (int)((threads + block - 1) / block);
        edge_decoder_f16d_kernel<<<grid, block, 0, stream>>>(
            wu, wm, wr, idx, out, E);
    } else {
        long long threads = (long long)E * 4;
        int grid = (int)((threads + block - 1) / block);
        edge_decoder_f32_kernel<<<grid, block, 0, stream>>>(
            zu4, zm4, rel4, idx, out, E);
    }
}

// Round 7
// 114.456 us; speedup vs baseline: 1.4598x; 1.1149x over previous
//
#include <hip/hip_runtime.h>
#include <hip/hip_fp16.h>

#define H 64
#define R 5

typedef float    v2f __attribute__((ext_vector_type(2)));
typedef _Float16 v2h __attribute__((ext_vector_type(2)));

static __device__ __forceinline__ v2f fma2(v2f a, v2f b, v2f c) {
#if __has_builtin(__builtin_elementwise_fma)
    return __builtin_elementwise_fma(a, b, c);
#else
    return a * b + c;
#endif
}

// fp16 2-way dot with fp32 accumulate: v_dot2_f32_f16
static __device__ __forceinline__ float dot2(v2h a, v2h b, float c) {
#if __has_builtin(__builtin_amdgcn_fdot2)
    return __builtin_amdgcn_fdot2(a, b, c, false);
#else
    return (float)a.x * (float)b.x + (float)a.y * (float)b.y + c;
#endif
}

static __device__ __forceinline__ v2h bch(unsigned u) {
    return __builtin_bit_cast(v2h, u);
}

// pack two fp32 -> fp16 pair (RNE) in one uint
static __device__ __forceinline__ unsigned h2pair(float a, float b) {
    __half2 h = __floats2half2_rn(a, b);
    return *(const unsigned*)&h;
}

// Streaming prep: z_user, z_movie AND rel_emb -> fp16 in workspace.
__global__ __launch_bounds__(256) void convert_f16_kernel(
    const float4* __restrict__ zu4, const float4* __restrict__ zm4,
    const float4* __restrict__ rel4,
    uint4* __restrict__ wu, uint4* __restrict__ wm, uint4* __restrict__ wr,
    int n_u_chunks, int n_m_chunks, int n_r_chunks)
{
    int t = blockIdx.x * blockDim.x + threadIdx.x;
    const float4* src;
    uint4* dst;
    int c;
    if (t < n_u_chunks)                   { src = zu4;  dst = wu; c = t; }
    else if (t < n_u_chunks + n_m_chunks) { src = zm4;  dst = wm; c = t - n_u_chunks; }
    else if (t < n_u_chunks + n_m_chunks + n_r_chunks)
                                          { src = rel4; dst = wr; c = t - n_u_chunks - n_m_chunks; }
    else return;
    float4 f0 = src[2 * c];
    float4 f1 = src[2 * c + 1];
    uint4 o;
    o.x = h2pair(f0.x, f0.y);
    o.y = h2pair(f0.z, f0.w);
    o.z = h2pair(f1.x, f1.y);
    o.w = h2pair(f1.z, f1.w);
    dst[c] = o;
}

// Main pass: quad handles 4 edges; ALL hot-path code is macro-generated
// straight-line with named scalars only — no arrays (round 6's s[R][4] was
// demoted to LDS by AMDGPUPromoteAlloca: LDS_Block_Size=20480, 593k bank
// conflicts, loads re-rolled to 4-deep). 16 independent row loads issued
// back-to-back for latency overlap; rel fragments preloaded to regs;
// per-r score/butterfly/mux scoped so temporaries die.
// Lane l of a quad reads 16B chunk l and 4+l of each 128B row -> one
// contiguous 64B line per quad per load instr (minimal 4 line txns/edge).
// Lane l owns edge base+l for softmax (all 64 lanes active, coalesced store).
__global__ __launch_bounds__(256) void edge_decoder_f16s_kernel(
    const uint4* __restrict__ wu,    // fp16 rows, 8 uint4 per row
    const uint4* __restrict__ wm,
    const uint4* __restrict__ wr,    // fp16 rel_emb, 8 uint4 per relation
    const int*   __restrict__ idx,
    float*       __restrict__ out,
    int E)
{
    int tid  = blockIdx.x * blockDim.x + threadIdx.x;
    int l    = tid & 3;
    int base = tid & ~3;
    if (base >= E) return;          // whole quad out of range

    int su_l = 0, sm_l = 0;
    if (tid < E) { su_l = idx[tid]; sm_l = idx[E + tid]; }

    int su0 = __shfl(su_l, 0, 4);
    int su1 = __shfl(su_l, 1, 4);
    int su2 = __shfl(su_l, 2, 4);
    int su3 = __shfl(su_l, 3, 4);
    int sm0 = __shfl(sm_l, 0, 4);
    int sm1 = __shfl(sm_l, 1, 4);
    int sm2 = __shfl(sm_l, 2, 4);
    int sm3 = __shfl(sm_l, 3, 4);

    // 16 independent row loads, issued back-to-back (the L2-miss traffic)
#define ROWS(j)                                          \
    uint4 a0_##j = wu[(size_t)su##j * 8 + l];            \
    uint4 a1_##j = wu[(size_t)su##j * 8 + 4 + l];        \
    uint4 b0_##j = wm[(size_t)sm##j * 8 + l];            \
    uint4 b1_##j = wm[(size_t)sm##j * 8 + 4 + l];
    ROWS(0) ROWS(1) ROWS(2) ROWS(3)
#undef ROWS

    // rel fragments (L1/L2-resident): w0_r covers h in [8l,8l+8),
    // w1_r covers h in [32+8l, 32+8l+8)
#define RELS(r)                                          \
    uint4 w0_##r = wr[r * 8 + l];                        \
    uint4 w1_##r = wr[r * 8 + 4 + l];
    RELS(0) RELS(1) RELS(2) RELS(3) RELS(4)
#undef RELS

    // products: 8 v2h per edge (v_pk_mul_f16); frees the row regs
#define MAKE_P(j)                                        \
    v2h p##j##_0 = bch(a0_##j.x) * bch(b0_##j.x);        \
    v2h p##j##_1 = bch(a0_##j.y) * bch(b0_##j.y);        \
    v2h p##j##_2 = bch(a0_##j.z) * bch(b0_##j.z);        \
    v2h p##j##_3 = bch(a0_##j.w) * bch(b0_##j.w);        \
    v2h p##j##_4 = bch(a1_##j.x) * bch(b1_##j.x);        \
    v2h p##j##_5 = bch(a1_##j.y) * bch(b1_##j.y);        \
    v2h p##j##_6 = bch(a1_##j.z) * bch(b1_##j.z);        \
    v2h p##j##_7 = bch(a1_##j.w) * bch(b1_##j.w);
    MAKE_P(0) MAKE_P(1) MAKE_P(2) MAKE_P(3)
#undef MAKE_P

    bool c1 = (l & 1) != 0;
    bool c2 = (l & 2) != 0;

    // 8-term fp16 dot (fp32 accum) for edge j, relation r
#define SCORE(j, r)                                                   \
    dot2(p##j##_7, bch(w1_##r.w), dot2(p##j##_6, bch(w1_##r.z),       \
    dot2(p##j##_5, bch(w1_##r.y), dot2(p##j##_4, bch(w1_##r.x),       \
    dot2(p##j##_3, bch(w0_##r.w), dot2(p##j##_2, bch(w0_##r.z),       \
    dot2(p##j##_1, bch(w0_##r.y), dot2(p##j##_0, bch(w0_##r.x), 0.f))))))))

    float sc0, sc1, sc2, sc3, sc4;
    // per-r: 4 partial scores, quad butterfly, then lane l muxes out its
    // own edge's value — temporaries die at the closing brace.
#define REDUCE(r, scr) {                                              \
        float s0 = SCORE(0, r);                                       \
        float s1 = SCORE(1, r);                                       \
        float s2 = SCORE(2, r);                                       \
        float s3 = SCORE(3, r);                                       \
        s0 += __shfl_xor(s0, 1); s1 += __shfl_xor(s1, 1);             \
        s2 += __shfl_xor(s2, 1); s3 += __shfl_xor(s3, 1);             \
        s0 += __shfl_xor(s0, 2); s1 += __shfl_xor(s1, 2);             \
        s2 += __shfl_xor(s2, 2); s3 += __shfl_xor(s3, 2);             \
        scr = c2 ? (c1 ? s3 : s2) : (c1 ? s1 : s0);                   \
    }
    REDUCE(0, sc0) REDUCE(1, sc1) REDUCE(2, sc2) REDUCE(3, sc3) REDUCE(4, sc4)
#undef REDUCE
#undef SCORE

    float mx = fmaxf(fmaxf(fmaxf(sc0, sc1), fmaxf(sc2, sc3)), sc4);
    float e0 = __expf(sc0 - mx);
    float e1 = __expf(sc1 - mx);
    float e2 = __expf(sc2 - mx);
    float e3 = __expf(sc3 - mx);
    float e4 = __expf(sc4 - mx);
    float den = e0 + e1 + e2 + e3 + e4;
    float num = fmaf(4.f, e4, fmaf(3.f, e3, fmaf(2.f, e2, e1)));
    if (tid < E) out[tid] = num * __frcp_rn(den);
}

// ---- fp32 fallback (round-3 kernel) if ws is too small for fp16 tables ----
__global__ __launch_bounds__(256) void edge_decoder_f32_kernel(
    const float4* __restrict__ zu4, const float4* __restrict__ zm4,
    const float4* __restrict__ rel4, const int* __restrict__ idx,
    float* __restrict__ out, int E)
{
    int tid = blockIdx.x * blockDim.x + threadIdx.x;
    int l   = threadIdx.x & 3;
    int e   = tid >> 2;
    if (e >= E) return;
    int su = idx[e];
    int sm = idx[E + e];
    const float4* arow = zu4 + su * 16;
    const float4* brow = zm4 + sm * 16;
    v2f plo[4], phi[4];
#pragma unroll
    for (int i = 0; i < 4; ++i) {
        float4 av = arow[4 * i + l];
        float4 bv = brow[4 * i + l];
        v2f alo = {av.x, av.y}, ahi = {av.z, av.w};
        v2f blo = {bv.x, bv.y}, bhi = {bv.z, bv.w};
        plo[i] = alo * blo;
        phi[i] = ahi * bhi;
    }
    float s[R];
#pragma unroll
    for (int r = 0; r < R; ++r) {
        v2f acc = {0.f, 0.f};
#pragma unroll
        for (int i = 0; i < 4; ++i) {
            float4 w = rel4[r * 16 + 4 * i + l];
            acc = fma2(plo[i], (v2f){w.x, w.y}, acc);
            acc = fma2(phi[i], (v2f){w.z, w.w}, acc);
        }
        s[r] = acc.x + acc.y;
    }
#pragma unroll
    for (int r = 0; r < R; ++r) s[r] += __shfl_xor(s[r], 1);
#pragma unroll
    for (int r = 0; r < R; ++r) s[r] += __shfl_xor(s[r], 2);
    if (l == 0) {
        float mx = fmaxf(fmaxf(fmaxf(s[0], s[1]), fmaxf(s[2], s[3])), s[4]);
        float e0 = __expf(s[0] - mx);
        float e1 = __expf(s[1] - mx);
        float e2 = __expf(s[2] - mx);
        float e3 = __expf(s[3] - mx);
        float e4 = __expf(s[4] - mx);
        float den = e0 + e1 + e2 + e3 + e4;
        float num = fmaf(4.f, e4, fmaf(3.f, e3, fmaf(2.f, e2, e1)));
        out[e] = num * __frcp_rn(den);
    }
}

extern "C" void kernel_launch(void* const* d_in, const int* in_sizes, int n_in,
                              void* d_out, int out_size, void* d_ws, size_t ws_size,
                              hipStream_t stream) {
    const float4* zu4  = (const float4*)d_in[0];   // z_user   [NU,64]
    const float4* zm4  = (const float4*)d_in[1];   // z_movie  [NM,64]
    const float4* rel4 = (const float4*)d_in[2];   // rel_emb  [5,64]
    const int*    idx  = (const int*)d_in[3];      // edge_label_index [2,E]
    float* out = (float*)d_out;

    int E  = in_sizes[3] / 2;
    int nu = in_sizes[0] / H;   // user rows
    int nm = in_sizes[1] / H;   // movie rows

    size_t need = (size_t)(nu + nm + R) * H * 2;   // fp16 tables + rel
    int block = 256;

    if (ws_size >= need) {
        uint4* wu = (uint4*)d_ws;              // nu*8 uint4
        uint4* wm = wu + (size_t)nu * 8;       // nm*8 uint4
        uint4* wr = wm + (size_t)nm * 8;       // R*8 uint4

        int n_u_chunks = nu * (H / 8);
        int n_m_chunks = nm * (H / 8);
        int n_r_chunks = R * (H / 8);
        int conv_threads = n_u_chunks + n_m_chunks + n_r_chunks;
        int conv_grid = (conv_threads + block - 1) / block;
        convert_f16_kernel<<<conv_grid, block, 0, stream>>>(
            zu4, zm4, rel4, wu, wm, wr, n_u_chunks, n_m_chunks, n_r_chunks);

        long long threads = (long long)E;      // 1 lane per edge owned
        int grid = (int)((threads + block - 1) / block);
        edge_decoder_f16s_kernel<<<grid, block, 0, stream>>>(
            wu, wm, wr, idx, out, E);
    } else {
        long long threads = (long long)E * 4;
        int grid = (int)((threads + block - 1) / block);
        edge_decoder_f32_kernel<<<grid, block, 0, stream>>>(
            zu4, zm4, rel4, idx, out, E);
    }
}